// Round 13
// baseline (431.896 us; speedup 1.0000x reference)
//
#include <hip/hip_runtime.h>

#define DD 256
#define TOTROWS (524288 * 2)
#define NBLOCKS 512
#define RPI 32                               // rows per region per block
#define ITERS (TOTROWS / (NBLOCKS * RPI))    // 64
#define XROW 528                             // bf16 x row stride (bytes)
#define XBUF(i) ((i) * (RPI * XROW))         // 2 x tiles: 33792 B
#define YB (2 * RPI * XROW)                  // fp32 y tile (single): 33280 B
#define YROW 1040                            // fp32 y row stride = 65*16 B
#define SUMSB (YB + RPI * YROW)              // 32 rows x 40 B partials
#define MURSB (SUMSB + RPI * 40)             // 32 x {mu, rs}
#define GBOF (MURSB + RPI * 8)               // gamma | beta (fp32, 1 KiB each)
#define LDS_TOTAL (GBOF + 2048)              // 70656 B -> 2 blocks/CU

typedef __attribute__((ext_vector_type(8))) short short8;
typedef __attribute__((ext_vector_type(4))) float f32x4;
typedef __attribute__((ext_vector_type(2))) float f32x2;
typedef __attribute__((ext_vector_type(4))) unsigned short u16x4;
typedef __attribute__((ext_vector_type(4))) unsigned int u32x4;

__device__ inline unsigned short f2bf(float x) {
    unsigned u = __builtin_bit_cast(unsigned, x);
    u += 0x7fffu + ((u >> 16) & 1u);  // RNE (wprep only)
    return (unsigned short)(u >> 16);
}
__device__ inline float bf2f(unsigned short h) {
    unsigned u = ((unsigned)h) << 16;
    return __builtin_bit_cast(float, u);
}
// HW packed f32->bf16 (RNE): lo -> [15:0], hi -> [31:16]
__device__ inline unsigned cvtpk(float lo, float hi) {
    unsigned r;
    asm("v_cvt_pk_bf16_f32 %0, %1, %2" : "=v"(r) : "v"(lo), "v"(hi));
    return r;
}

// LDS-only barrier: orders ds ops across waves WITHOUT draining in-flight
// global loads/stores (vmcnt untouched). All cross-wave hazards are LDS.
__device__ inline void block_sync_lds() {
    __builtin_amdgcn_sched_barrier(0);
    asm volatile("s_waitcnt lgkmcnt(0)" ::: "memory");
    __builtin_amdgcn_s_barrier();
    __builtin_amdgcn_sched_barrier(0);
}

// ---------------- W = Wo @ Wv (bf16), c = Wo @ bv + bo ----------------
__global__ void wprep_kernel(const float* __restrict__ in_w,
                             const float* __restrict__ in_b,
                             const float* __restrict__ out_w,
                             const float* __restrict__ out_b,
                             unsigned short* __restrict__ Wbf,
                             float* __restrict__ cvec) {
    __shared__ float worow[DD];
    __shared__ float part[DD];
    const int i = blockIdx.x;
    const int j = threadIdx.x;
    worow[j] = out_w[i * DD + j];
    __syncthreads();
    const float* wv = in_w + 512 * DD;  // Wv = rows 512..767 of in_proj_w
    float s = 0.f;
    for (int k = 0; k < DD; ++k) s = fmaf(worow[k], wv[k * DD + j], s);
    Wbf[i * DD + j] = f2bf(s);
    part[j] = worow[j] * in_b[512 + j];  // bv[j]
    __syncthreads();
    if (j == 0) {
        float c = out_b[i];
        for (int k = 0; k < DD; ++k) c += part[k];
        cvec[i] = c;
    }
}

// ---------------- main fused kernel ----------------
// 512 blocks x 256 threads (4 waves), TWO independent blocks per CU
// (VGPR ~235 <= 256 -> 2 waves/SIMD; LDS 70.7 KB x2 = 141 KB). Each wave
// owns 64 W-cols (af = 128 VGPRs). acc lives within one region only.
// Region: [S: store y(it-1) | C: MFMA+residual+partials | D: stage+loads]
// bar [A: reduce] bar [B: finalize -> ybuf] bar. Blocks desync -> one
// block's loads/stores fill the other's reduce/finalize bubbles.
__global__ __launch_bounds__(256, 2) void fused_kernel(
    const float* __restrict__ x, const unsigned short* __restrict__ Wbf,
    const float* __restrict__ cvec, const float* __restrict__ gamma,
    const float* __restrict__ beta, float* __restrict__ out) {
    extern __shared__ __align__(16) char lds[];
    const int tid = threadIdx.x;
    const int w = tid >> 6, lane = tid & 63;
    const int m = lane & 15, g = lane >> 4;
    const int st_r = tid >> 5, st_c = tid & 31;  // staging: sub-row / 16B chunk

    // A fragments: af[n2][s] = W[w*64+n2*16+m][s*32+g*8 ..]  (128 VGPRs)
    short8 af[4][8];
#pragma unroll
    for (int n2 = 0; n2 < 4; ++n2)
#pragma unroll
        for (int s = 0; s < 8; ++s)
            af[n2][s] = *(const short8*)(Wbf + (w * 64 + n2 * 16 + m) * 256 + s * 32 + g * 8);

    f32x4 creg[4];
#pragma unroll
    for (int n2 = 0; n2 < 4; ++n2)
        creg[n2] = *(const f32x4*)(cvec + w * 64 + n2 * 16 + g * 4);

    // gamma/beta -> LDS (saves 32 VGPRs)
    *(float*)(lds + GBOF + tid * 4) = gamma[tid];
    *(float*)(lds + GBOF + 1024 + tid * 4) = beta[tid];

    const size_t rowbase = (size_t)blockIdx.x * (ITERS * RPI);

    f32x4 sva[4], svb[4];  // 32 VGPRs: 32B/thread x 4 row-groups

    // prologue: load+stage tile 0 -> xbuf0; issue loads for tile 1
#pragma unroll
    for (int j2 = 0; j2 < 4; ++j2) {
        const int row = j2 * 8 + st_r;
        sva[j2] = *(const f32x4*)(x + (rowbase + row) * DD + st_c * 8);
        svb[j2] = *(const f32x4*)(x + (rowbase + row) * DD + st_c * 8 + 4);
    }
#pragma unroll
    for (int j2 = 0; j2 < 4; ++j2) {
        const int row = j2 * 8 + st_r;
        u32x4 h = {cvtpk(sva[j2][0], sva[j2][1]), cvtpk(sva[j2][2], sva[j2][3]),
                   cvtpk(svb[j2][0], svb[j2][1]), cvtpk(svb[j2][2], svb[j2][3])};
        *(u32x4*)(lds + XBUF(0) + row * XROW + st_c * 16) = h;
    }
#pragma unroll
    for (int j2 = 0; j2 < 4; ++j2) {
        const int row = j2 * 8 + st_r;
        sva[j2] = *(const f32x4*)(x + (rowbase + RPI + row) * DD + st_c * 8);
        svb[j2] = *(const f32x4*)(x + (rowbase + RPI + row) * DD + st_c * 8 + 4);
    }
    block_sync_lds();

    for (int it = 0; it < ITERS; ++it) {
        const int xbc = XBUF(it & 1);
        const int xbn = XBUF((it + 1) & 1);
        const size_t r0 = rowbase + (size_t)it * RPI;

        // S: coalesced nt-store of y(it-1) from ybuf (1KB/wave/instr)
        if (it > 0) {
            const size_t rp = r0 - RPI;
#pragma unroll
            for (int j = 0; j < 8; ++j) {
                const int row = j * 4 + w;
                f32x4 v = *(const f32x4*)(lds + YB + row * YROW + lane * 16);
                __builtin_nontemporal_store(v, (f32x4*)(out + (rp + row) * DD + lane * 4));
            }
        }

        // C: MFMA(it) -> acc (bias-init), residual, LN partials -> SUMS
        f32x4 acc[2][4];
#pragma unroll
        for (int t = 0; t < 2; ++t)
#pragma unroll
            for (int n2 = 0; n2 < 4; ++n2) acc[t][n2] = creg[n2];
#pragma unroll
        for (int t = 0; t < 2; ++t) {
            const int rowp = t * 16 + (m ^ 1);  // partner row
            const char* bbase = lds + xbc + rowp * XROW + g * 16;
#pragma unroll
            for (int s = 0; s < 8; ++s) {
                short8 bf_ = *(const short8*)(bbase + s * 64);
#pragma unroll
                for (int n2 = 0; n2 < 4; ++n2)
                    acc[t][n2] = __builtin_amdgcn_mfma_f32_16x16x32_bf16(af[n2][s], bf_, acc[t][n2], 0, 0, 0);
            }
        }
#pragma unroll
        for (int t = 0; t < 2; ++t) {
            const int rowm = t * 16 + m;
            float s1 = 0.f, s2 = 0.f;
#pragma unroll
            for (int n2 = 0; n2 < 4; ++n2) {
                u16x4 rh = *(const u16x4*)(lds + xbc + rowm * XROW + (w * 64 + n2 * 16 + g * 4) * 2);
                f32x4 y = acc[t][n2];
#pragma unroll
                for (int i = 0; i < 4; ++i) y[i] += bf2f(rh[i]);
                acc[t][n2] = y;
#pragma unroll
                for (int i = 0; i < 4; ++i) {
                    s1 += y[i];
                    s2 = fmaf(y[i], y[i], s2);
                }
            }
            s1 += __shfl_xor(s1, 16); s2 += __shfl_xor(s2, 16);
            s1 += __shfl_xor(s1, 32); s2 += __shfl_xor(s2, 32);
            if (g == 0) *(f32x2*)(lds + SUMSB + rowm * 40 + w * 8) = f32x2{s1, s2};
        }

        // D: stage sv (tile it+1) -> xbn; issue loads for tile it+2
        if (it + 1 < ITERS) {
#pragma unroll
            for (int j2 = 0; j2 < 4; ++j2) {
                const int row = j2 * 8 + st_r;
                u32x4 h = {cvtpk(sva[j2][0], sva[j2][1]), cvtpk(sva[j2][2], sva[j2][3]),
                           cvtpk(svb[j2][0], svb[j2][1]), cvtpk(svb[j2][2], svb[j2][3])};
                *(u32x4*)(lds + xbn + row * XROW + st_c * 16) = h;
            }
        }
        if (it + 2 < ITERS) {
#pragma unroll
            for (int j2 = 0; j2 < 4; ++j2) {
                const int row = j2 * 8 + st_r;
                sva[j2] = *(const f32x4*)(x + (r0 + 2 * RPI + row) * DD + st_c * 8);
                svb[j2] = *(const f32x4*)(x + (r0 + 2 * RPI + row) * DD + st_c * 8 + 4);
            }
        }
        block_sync_lds();  // bar1

        // A: cooperative reduce SUMS -> MURS (32 rows x 4 partials, waves 0-1)
        if (tid < 128) {
            const int row = tid >> 2, p = tid & 3;
            f32x2 pp = *(const f32x2*)(lds + SUMSB + row * 40 + p * 8);
            float a = pp[0], b = pp[1];
            a += __shfl_xor(a, 1); b += __shfl_xor(b, 1);
            a += __shfl_xor(a, 2); b += __shfl_xor(b, 2);
            if (p == 0) {
                const float mu = a * (1.f / 256.f);
                const float var = b * (1.f / 256.f) - mu * mu;
                *(f32x2*)(lds + MURSB + row * 8) = f32x2{mu, rsqrtf(var + 1e-5f)};
            }
        }
        block_sync_lds();  // bar2

        // B: finalize acc -> ybuf fp32
#pragma unroll
        for (int t = 0; t < 2; ++t) {
            f32x2 mr = *(const f32x2*)(lds + MURSB + (t * 16 + m) * 8);
#pragma unroll
            for (int n2 = 0; n2 < 4; ++n2) {
                const int c0 = w * 64 + n2 * 16 + g * 4;
                f32x4 gv = *(const f32x4*)(lds + GBOF + c0 * 4);
                f32x4 bv = *(const f32x4*)(lds + GBOF + 1024 + c0 * 4);
                f32x4 y = acc[t][n2], o;
#pragma unroll
                for (int i = 0; i < 4; ++i)
                    o[i] = fmaf((y[i] - mr[0]) * mr[1], gv[i], bv[i]);
                *(f32x4*)(lds + YB + (t * 16 + m) * YROW + c0 * 4) = o;
            }
        }
        block_sync_lds();  // bar3
    }

    // epilogue: store y(ITERS-1) from ybuf
    {
        const size_t rp = rowbase + (size_t)(ITERS - 1) * RPI;
#pragma unroll
        for (int j = 0; j < 8; ++j) {
            const int row = j * 4 + w;
            f32x4 v = *(const f32x4*)(lds + YB + row * YROW + lane * 16);
            __builtin_nontemporal_store(v, (f32x4*)(out + (rp + row) * DD + lane * 4));
        }
    }
}

extern "C" void kernel_launch(void* const* d_in, const int* in_sizes, int n_in,
                              void* d_out, int out_size, void* d_ws, size_t ws_size,
                              hipStream_t stream) {
    const float* x     = (const float*)d_in[0];
    const float* in_w  = (const float*)d_in[1];
    const float* in_b  = (const float*)d_in[2];
    const float* out_w = (const float*)d_in[3];
    const float* out_b = (const float*)d_in[4];
    const float* gamma = (const float*)d_in[5];
    const float* beta  = (const float*)d_in[6];
    float* out = (float*)d_out;

    unsigned short* Wbf = (unsigned short*)d_ws;   // 128 KiB bf16 W = Wo@Wv
    float* cvec = (float*)((char*)d_ws + 131072);  // 1 KiB c = Wo@bv + bo

    hipLaunchKernelGGL(wprep_kernel, dim3(256), dim3(256), 0, stream,
                       in_w, in_b, out_w, out_b, Wbf, cvec);

    hipFuncSetAttribute(reinterpret_cast<const void*>(fused_kernel),
                        hipFuncAttributeMaxDynamicSharedMemorySize, LDS_TOTAL);
    hipLaunchKernelGGL(fused_kernel, dim3(NBLOCKS), dim3(256), LDS_TOTAL, stream,
                       x, Wbf, cvec, gamma, beta, out);
}

// Round 14
// 397.833 us; speedup vs baseline: 1.0856x; 1.0856x over previous
//
#include <hip/hip_runtime.h>

#define DD 256
#define TOTROWS (524288 * 2)
#define NBLOCKS 256
#define RPI 64                               // rows per region per block
#define ITERS (TOTROWS / (NBLOCKS * RPI))    // 64
#define XROW 528                             // bf16 x row stride (bytes)
#define XBUF(i) ((i) * (RPI * XROW))         // 2 x tiles: 67584 B
#define YB (2 * RPI * XROW)                  // fp32 normalized-y tile (single)
#define YROW 1040                            // fp32 y row stride = 65*16 B
#define SUMSB (YB + RPI * YROW)              // 64 rows x 72 B partials
#define MURSB (SUMSB + RPI * 72)             // 64 x {mu, rs}
#define LDS_TOTAL (MURSB + RPI * 8)          // 139264 B -> 1 block/CU

typedef __attribute__((ext_vector_type(8))) short short8;
typedef __attribute__((ext_vector_type(4))) float f32x4;
typedef __attribute__((ext_vector_type(2))) float f32x2;
typedef __attribute__((ext_vector_type(4))) unsigned short u16x4;
typedef __attribute__((ext_vector_type(2))) unsigned int u32x2;

__device__ inline unsigned short f2bf(float x) {
    unsigned u = __builtin_bit_cast(unsigned, x);
    u += 0x7fffu + ((u >> 16) & 1u);  // RNE (wprep only)
    return (unsigned short)(u >> 16);
}
__device__ inline float bf2f(unsigned short h) {
    unsigned u = ((unsigned)h) << 16;
    return __builtin_bit_cast(float, u);
}
// HW packed f32->bf16 (RNE): lo -> [15:0], hi -> [31:16]
__device__ inline unsigned cvtpk(float lo, float hi) {
    unsigned r;
    asm("v_cvt_pk_bf16_f32 %0, %1, %2" : "=v"(r) : "v"(lo), "v"(hi));
    return r;
}

// LDS-only barrier: orders ds ops across waves WITHOUT draining in-flight
// global loads/stores (vmcnt untouched). All cross-wave hazards are LDS.
__device__ inline void block_sync_lds() {
    __builtin_amdgcn_sched_barrier(0);
    asm volatile("s_waitcnt lgkmcnt(0)" ::: "memory");
    __builtin_amdgcn_s_barrier();
    __builtin_amdgcn_sched_barrier(0);
}

// ---------------- W = Wo @ Wv (bf16), c = Wo @ bv + bo ----------------
__global__ void wprep_kernel(const float* __restrict__ in_w,
                             const float* __restrict__ in_b,
                             const float* __restrict__ out_w,
                             const float* __restrict__ out_b,
                             unsigned short* __restrict__ Wbf,
                             float* __restrict__ cvec) {
    __shared__ float worow[DD];
    __shared__ float part[DD];
    const int i = blockIdx.x;
    const int j = threadIdx.x;
    worow[j] = out_w[i * DD + j];
    __syncthreads();
    const float* wv = in_w + 512 * DD;  // Wv = rows 512..767 of in_proj_w
    float s = 0.f;
    for (int k = 0; k < DD; ++k) s = fmaf(worow[k], wv[k * DD + j], s);
    Wbf[i * DD + j] = f2bf(s);
    part[j] = worow[j] * in_b[512 + j];  // bv[j]
    __syncthreads();
    if (j == 0) {
        float c = out_b[i];
        for (int k = 0; k < DD; ++k) c += part[k];
        cvec[i] = c;
    }
}

// ---------------- main fused kernel ----------------
// Per region: [S: coalesced nt-store of y(it-2) rows from fp32 ybuf |
// A: reduce SUMS(it-1) -> MURS] alpha [B1: finalize acc(it-1) -> ybuf |
// C: MFMA(it) -> acc, residual, LN partials from regs -> SUMS |
// D: stage x(it+1), issue loads x(it+2)] beta.
// No bf16 y round-trip; LN sums overlap MFMA phase; stores 1KB/wave.
__global__ __launch_bounds__(512, 2) void fused_kernel(
    const float* __restrict__ x, const unsigned short* __restrict__ Wbf,
    const float* __restrict__ cvec, const float* __restrict__ gamma,
    const float* __restrict__ beta, float* __restrict__ out) {
    extern __shared__ __align__(16) char lds[];
    const int tid = threadIdx.x;
    const int w = tid >> 6, lane = tid & 63;
    const int m = lane & 15, g = lane >> 4;
    const int ar = tid >> 3, ap = tid & 7;  // reduce: row 0..63 / partial 0..7

    // A fragments: af[n2][s] = W[w*32+n2*16+m][s*32+g*8 ..]  (64 VGPRs)
    short8 af[2][8];
#pragma unroll
    for (int n2 = 0; n2 < 2; ++n2)
#pragma unroll
        for (int s = 0; s < 8; ++s)
            af[n2][s] = *(const short8*)(Wbf + (w * 32 + n2 * 16 + m) * 256 + s * 32 + g * 8);

    f32x4 creg[2], gg[2], bbv[2];
#pragma unroll
    for (int n2 = 0; n2 < 2; ++n2) {
        const int c0 = w * 32 + n2 * 16 + g * 4;
        creg[n2] = *(const f32x4*)(cvec + c0);
        gg[n2]   = *(const f32x4*)(gamma + c0);
        bbv[n2]  = *(const f32x4*)(beta + c0);
    }

    const size_t rowbase = (size_t)blockIdx.x * (ITERS * RPI);

    f32x4 sv[8];
    f32x4 accA[4][2], accB[4][2];

    // prologue: load+stage tile 0 -> xbuf0; issue loads for tile 1
#pragma unroll
    for (int j = 0; j < 8; ++j)
        sv[j] = *(const f32x4*)(x + rowbase * DD + j * 2048 + tid * 4);
#pragma unroll
    for (int j = 0; j < 8; ++j) {
        const int row = j * 8 + w;
        u32x2 h = {cvtpk(sv[j][0], sv[j][1]), cvtpk(sv[j][2], sv[j][3])};
        *(u32x2*)(lds + XBUF(0) + row * XROW + lane * 8) = h;
    }
#pragma unroll
    for (int j = 0; j < 8; ++j)
        sv[j] = *(const f32x4*)(x + (rowbase + RPI) * DD + j * 2048 + tid * 4);
    block_sync_lds();

#define REGION(IT, ACCP, ACCC)                                                   \
    {                                                                            \
        const int it = (IT);                                                     \
        const int xbc = XBUF(it & 1);                                            \
        const int xbn = XBUF((it + 1) & 1);                                      \
        const size_t r0 = rowbase + (size_t)it * RPI;                            \
        /* S: coalesced nt-store of y(it-2) from ybuf (1KB/wave/instr) */        \
        if (it > 1) {                                                            \
            const size_t rs_ = r0 - 2 * RPI;                                     \
            _Pragma("unroll")                                                    \
            for (int j = 0; j < 8; ++j) {                                        \
                const int row = j * 8 + w;                                       \
                f32x4 v = *(const f32x4*)(lds + YB + row * YROW + lane * 16);    \
                __builtin_nontemporal_store(v,                                   \
                    (f32x4*)(out + (rs_ + row) * DD + lane * 4));                \
            }                                                                    \
        }                                                                        \
        /* A: cooperative reduce SUMS(it-1) -> MURS */                           \
        if (it > 0) {                                                            \
            f32x2 p = *(const f32x2*)(lds + SUMSB + ar * 72 + ap * 8);           \
            float a = p[0], b = p[1];                                            \
            a += __shfl_xor(a, 1); b += __shfl_xor(b, 1);                        \
            a += __shfl_xor(a, 2); b += __shfl_xor(b, 2);                        \
            a += __shfl_xor(a, 4); b += __shfl_xor(b, 4);                        \
            if (ap == 0) {                                                       \
                const float mu = a * (1.f / 256.f);                              \
                const float var = b * (1.f / 256.f) - mu * mu;                   \
                *(f32x2*)(lds + MURSB + ar * 8) = f32x2{mu, rsqrtf(var + 1e-5f)};\
            }                                                                    \
        }                                                                        \
        block_sync_lds(); /* alpha */                                            \
        /* B1: finalize ACCP (region it-1) -> ybuf fp32 (balanced banks) */      \
        if (it > 0) {                                                            \
            _Pragma("unroll")                                                    \
            for (int t = 0; t < 4; ++t) {                                        \
                f32x2 mr = *(const f32x2*)(lds + MURSB + (t * 16 + m) * 8);      \
                _Pragma("unroll")                                                \
                for (int n2 = 0; n2 < 2; ++n2) {                                 \
                    f32x4 y = ACCP[t][n2], o;                                    \
                    _Pragma("unroll")                                            \
                    for (int i = 0; i < 4; ++i)                                  \
                        o[i] = fmaf((y[i] - mr[0]) * mr[1], gg[n2][i], bbv[n2][i]); \
                    *(f32x4*)(lds + YB + (t * 16 + m) * YROW +                   \
                              (w * 32 + n2 * 16 + g * 4) * 4) = o;               \
                }                                                                \
            }                                                                    \
        }                                                                        \
        /* C: MFMA(it) -> ACCC (bias-init), residual, LN partials -> SUMS */     \
        _Pragma("unroll")                                                        \
        for (int t = 0; t < 4; ++t) {                                            \
            ACCC[t][0] = creg[0];                                                \
            ACCC[t][1] = creg[1];                                                \
        }                                                                        \
        _Pragma("unroll")                                                        \
        for (int t = 0; t < 4; ++t) {                                            \
            const int rowp = t * 16 + (m ^ 1);                                   \
            const char* bbase = lds + xbc + rowp * XROW + g * 16;                \
            _Pragma("unroll")                                                    \
            for (int s = 0; s < 8; ++s) {                                        \
                short8 bf_ = *(const short8*)(bbase + s * 64);                   \
                ACCC[t][0] = __builtin_amdgcn_mfma_f32_16x16x32_bf16(af[0][s], bf_, ACCC[t][0], 0, 0, 0); \
                ACCC[t][1] = __builtin_amdgcn_mfma_f32_16x16x32_bf16(af[1][s], bf_, ACCC[t][1], 0, 0, 0); \
            }                                                                    \
        }                                                                        \
        _Pragma("unroll")                                                        \
        for (int t = 0; t < 4; ++t) {                                            \
            const int rowm = t * 16 + m;                                         \
            float s1 = 0.f, s2 = 0.f;                                            \
            _Pragma("unroll")                                                    \
            for (int n2 = 0; n2 < 2; ++n2) {                                     \
                u16x4 rh = *(const u16x4*)(lds + xbc + rowm * XROW + w * 64 + n2 * 32 + g * 8); \
                f32x4 y = ACCC[t][n2];                                           \
                _Pragma("unroll")                                                \
                for (int i = 0; i < 4; ++i) y[i] += bf2f(rh[i]);                 \
                ACCC[t][n2] = y;                                                 \
                _Pragma("unroll")                                                \
                for (int i = 0; i < 4; ++i) {                                    \
                    s1 += y[i];                                                  \
                    s2 = fmaf(y[i], y[i], s2);                                   \
                }                                                                \
            }                                                                    \
            s1 += __shfl_xor(s1, 16); s2 += __shfl_xor(s2, 16);                  \
            s1 += __shfl_xor(s1, 32); s2 += __shfl_xor(s2, 32);                  \
            if (g == 0)                                                          \
                *(f32x2*)(lds + SUMSB + rowm * 72 + w * 8) = f32x2{s1, s2};      \
        }                                                                        \
        /* D: stage sv (tile it+1) -> xbn; issue loads for tile it+2 */          \
        if (it + 1 < ITERS) {                                                    \
            _Pragma("unroll")                                                    \
            for (int j = 0; j < 8; ++j) {                                        \
                const int row = j * 8 + w;                                       \
                u32x2 h = {cvtpk(sv[j][0], sv[j][1]), cvtpk(sv[j][2], sv[j][3])};\
                *(u32x2*)(lds + xbn + row * XROW + lane * 8) = h;                \
            }                                                                    \
        }                                                                        \
        if (it + 2 < ITERS) {                                                    \
            _Pragma("unroll")                                                    \
            for (int j = 0; j < 8; ++j)                                          \
                sv[j] = *(const f32x4*)(x + (r0 + 2 * RPI) * DD + j * 2048 + tid * 4); \
        }                                                                        \
        block_sync_lds(); /* beta */                                             \
    }

    for (int itb = 0; itb < ITERS; itb += 2) {
        REGION(itb, accB, accA);
        REGION(itb + 1, accA, accB);
    }
#undef REGION

    // epilogue: ybuf holds y(ITERS-2); acc(ITERS-1) in accB; SUMS holds its sums.
    {
        // S: store y(ITERS-2)
        const size_t rs_ = rowbase + (size_t)(ITERS - 2) * RPI;
#pragma unroll
        for (int j = 0; j < 8; ++j) {
            const int row = j * 8 + w;
            f32x4 v = *(const f32x4*)(lds + YB + row * YROW + lane * 16);
            __builtin_nontemporal_store(v, (f32x4*)(out + (rs_ + row) * DD + lane * 4));
        }
        // A: reduce SUMS -> MURS
        f32x2 p = *(const f32x2*)(lds + SUMSB + ar * 72 + ap * 8);
        float a = p[0], b = p[1];
        a += __shfl_xor(a, 1); b += __shfl_xor(b, 1);
        a += __shfl_xor(a, 2); b += __shfl_xor(b, 2);
        a += __shfl_xor(a, 4); b += __shfl_xor(b, 4);
        if (ap == 0) {
            const float mu = a * (1.f / 256.f);
            const float var = b * (1.f / 256.f) - mu * mu;
            *(f32x2*)(lds + MURSB + ar * 8) = f32x2{mu, rsqrtf(var + 1e-5f)};
        }
        block_sync_lds();
        // B1: finalize acc(ITERS-1) -> ybuf
#pragma unroll
        for (int t = 0; t < 4; ++t) {
            f32x2 mr = *(const f32x2*)(lds + MURSB + (t * 16 + m) * 8);
#pragma unroll
            for (int n2 = 0; n2 < 2; ++n2) {
                f32x4 y = accB[t][n2], o;
#pragma unroll
                for (int i = 0; i < 4; ++i)
                    o[i] = fmaf((y[i] - mr[0]) * mr[1], gg[n2][i], bbv[n2][i]);
                *(f32x4*)(lds + YB + (t * 16 + m) * YROW + (w * 32 + n2 * 16 + g * 4) * 4) = o;
            }
        }
        block_sync_lds();
        // S: store y(ITERS-1)
        const size_t rs2 = rowbase + (size_t)(ITERS - 1) * RPI;
#pragma unroll
        for (int j = 0; j < 8; ++j) {
            const int row = j * 8 + w;
            f32x4 v = *(const f32x4*)(lds + YB + row * YROW + lane * 16);
            __builtin_nontemporal_store(v, (f32x4*)(out + (rs2 + row) * DD + lane * 4));
        }
    }
}

extern "C" void kernel_launch(void* const* d_in, const int* in_sizes, int n_in,
                              void* d_out, int out_size, void* d_ws, size_t ws_size,
                              hipStream_t stream) {
    const float* x     = (const float*)d_in[0];
    const float* in_w  = (const float*)d_in[1];
    const float* in_b  = (const float*)d_in[2];
    const float* out_w = (const float*)d_in[3];
    const float* out_b = (const float*)d_in[4];
    const float* gamma = (const float*)d_in[5];
    const float* beta  = (const float*)d_in[6];
    float* out = (float*)d_out;

    unsigned short* Wbf = (unsigned short*)d_ws;   // 128 KiB bf16 W = Wo@Wv
    float* cvec = (float*)((char*)d_ws + 131072);  // 1 KiB c = Wo@bv + bo

    hipLaunchKernelGGL(wprep_kernel, dim3(256), dim3(256), 0, stream,
                       in_w, in_b, out_w, out_b, Wbf, cvec);

    hipFuncSetAttribute(reinterpret_cast<const void*>(fused_kernel),
                        hipFuncAttributeMaxDynamicSharedMemorySize, LDS_TOTAL);
    hipLaunchKernelGGL(fused_kernel, dim3(NBLOCKS), dim3(512), LDS_TOTAL, stream,
                       x, Wbf, cvec, gamma, beta, out);
}